// Round 4
// baseline (643.467 us; speedup 1.0000x reference)
//
#include <hip/hip_runtime.h>
#include <cstdint>

typedef unsigned short u16;
typedef __bf16 bf16x8 __attribute__((ext_vector_type(8)));
typedef float f32x4 __attribute__((ext_vector_type(4)));

#define B_    16
#define CIN   512
#define COUT  512
#define HW_   64
#define PW    66
#define C_EQ  1.4731391e-2f     // 1/sqrt(512*9)
#define XH_ELEMS ((size_t)B_*PW*PW*CIN)              // 35,684,352 u16 (71.4 MB)
#define WA_ELEMS ((size_t)B_*16*9*32*64*8)           // 37,748,736 u16 (75.5 MB)

__device__ __forceinline__ u16 f2bf(float f) {
  union { float f; unsigned int u; } c; c.f = f;
  unsigned int u = c.u + 0x7fffu + ((c.u >> 16) & 1u);   // RNE
  return (u16)(u >> 16);
}

__device__ __forceinline__ void async16(const void* g, void* l) {
  __builtin_amdgcn_global_load_lds(
      (__attribute__((address_space(1))) unsigned int*)(uintptr_t)g,
      (__attribute__((address_space(3))) unsigned int*)(uintptr_t)l,
      16, 0, 0);
}

// ---------------------------------------------------------------------------
// Kernel 1: zero the padding border of xh[b][66][66][512]
__global__ __launch_bounds__(256) void zero_border(u16* __restrict__ xh) {
  int g = blockIdx.x * 256 + threadIdx.x;
  if (g >= B_ * 260 * 64) return;
  int c8 = g & 63;
  int t  = g >> 6;
  int b  = t / 260;
  int p  = t - b * 260;
  int rp, cp;
  if (p < 66)       { rp = 0;      cp = p; }
  else if (p < 132) { rp = 65;     cp = p - 66; }
  else {
    int q = p - 132;
    if (q < 64) { rp = q + 1;  cp = 0; }
    else        { rp = q - 63; cp = 65; }
  }
  u16* dst = xh + ((((size_t)b * PW + rp) * PW + cp) << 9) + (c8 << 3);
  *(uint4*)dst = make_uint4(0u, 0u, 0u, 0u);
}

// ---------------------------------------------------------------------------
// Kernel 2: fp32 NCHW -> bf16 padded NHWC transpose
__global__ __launch_bounds__(256) void transpose_x(const float* __restrict__ x,
                                                   u16* __restrict__ xh) {
  __shared__ u16 tile[64][72];
  const int b  = blockIdx.z;
  const int y  = blockIdx.y;
  const int i0 = blockIdx.x * 64;
  const int t  = threadIdx.x;

  const int ciL = t >> 4;
  const int xg  = (t & 15) * 4;
#pragma unroll
  for (int u = 0; u < 4; ++u) {
    const int ci = ciL + u * 16;
    const float4 v = *(const float4*)(
        x + ((((size_t)b * CIN + i0 + ci) * HW_ + y) * HW_ + xg));
    u16* d = &tile[ci][xg];
    d[0] = f2bf(v.x); d[1] = f2bf(v.y); d[2] = f2bf(v.z); d[3] = f2bf(v.w);
  }
  __syncthreads();

  const int xx = t >> 2;
  const int cg = (t & 3) * 16;
  u16 outv[16];
#pragma unroll
  for (int u = 0; u < 16; ++u) outv[u] = tile[cg + u][xx];
  u16* dst = xh + ((((size_t)b * PW + (y + 1)) * PW + (xx + 1)) << 9) + i0 + cg;
  *(uint4*)dst       = *(uint4*)&outv[0];
  *(uint4*)(dst + 8) = *(uint4*)&outv[8];
}

// ---------------------------------------------------------------------------
// Kernel 3a: q[o][i] = sum_t w[o][i][t]^2   (512x512 fp32)
__global__ __launch_bounds__(256) void wsq_kernel(const float* __restrict__ w,
                                                  float* __restrict__ q) {
  const int idx = blockIdx.x * 256 + threadIdx.x;     // o*512+i, 262144 total
  const float* wp = w + (size_t)idx * 9;
  float acc = 0.f;
#pragma unroll
  for (int t = 0; t < 9; ++t) { float v = wp[t]; acc += v * v; }
  q[idx] = acc;
}

// Kernel 3b: sinv[b][o] = rsqrt(C^2 * sum_i s[b,i]^2 q[o,i] + eps)
__global__ __launch_bounds__(256) void sigma_kernel(const float* __restrict__ q,
                                                    const float* __restrict__ s,
                                                    float* __restrict__ sinv) {
  const int gwid = (blockIdx.x * 256 + threadIdx.x) >> 6;   // 0..8191
  const int lane = threadIdx.x & 63;
  const int b = gwid >> 9, o = gwid & 511;
  const float* qo = q + (size_t)o * 512;
  const float* sb = s + (size_t)b * 512;
  float acc = 0.f;
#pragma unroll
  for (int j = 0; j < 8; ++j) {
    const int i = lane + j * 64;
    const float sv = sb[i];
    acc += sv * sv * qo[i];
  }
#pragma unroll
  for (int off = 32; off > 0; off >>= 1) acc += __shfl_xor(acc, off, 64);
  if (lane == 0) sinv[b * 512 + o] = rsqrtf(acc * (C_EQ * C_EQ) + 1e-8f);
}

// Kernel 3c: write fragment-ordered modulated weights
// wAf[b][icc16][tap9][og32][lane64][j8] = wmod[o=og*16+(lane&15)]
//                                             [i=icc*32+(lane>>4)*8+j][tap]
__global__ __launch_bounds__(256) void write_wAf(const float* __restrict__ w,
                                                 const float* __restrict__ s,
                                                 const float* __restrict__ sinv,
                                                 u16* __restrict__ wAf) {
  const int icc = blockIdx.x / 9;
  const int tap = blockIdx.x - icc * 9;
  const int og  = blockIdx.y * 4 + (threadIdx.x >> 6);
  const int b   = blockIdx.z;
  const int lane = threadIdx.x & 63;
  const int l15 = lane & 15, qd = lane >> 4;

  const int o  = og * 16 + l15;
  const int i0 = icc * 32 + qd * 8;
  const float scb = C_EQ * sinv[b * 512 + o];
  const float* sb = s + (size_t)b * 512;
  const float* wp = w + ((size_t)o * 512 + i0) * 9 + tap;

  u16 tmp[8];
#pragma unroll
  for (int j = 0; j < 8; ++j)
    tmp[j] = f2bf(wp[(size_t)j * 9] * (scb * sb[i0 + j]));

  u16* dst = wAf + (((((size_t)b * 16 + icc) * 9 + tap) * 32 + og) * 64 + lane) * 8;
  *(uint4*)dst = *(uint4*)&tmp[0];
}

// ---------------------------------------------------------------------------
// Kernel 4: implicit-GEMM conv.
// Block = 256 o x 128 px (2 rows), 4 waves, wave tile 128 o x 64 px.
// A fragment-ordered (conflict-free), double-buffered, 1 barrier/tap.
// Bs rows padded to 40 el (80 B) -> 2-way (free) bank pattern.
__global__ __launch_bounds__(256, 2) void modconv_mfma(
    const u16* __restrict__ xh, const u16* __restrict__ wAf,
    const float* __restrict__ bias, float* __restrict__ out) {
  __shared__ __align__(16) u16 Asf[2][8192];   // [buf][og16][lane64][j8]  2x16 KB
  __shared__ __align__(16) u16 Bs[264 * 40];   // [rc][40]                 21.1 KB

  const int tid  = threadIdx.x;
  const int lane = tid & 63;
  const int wv   = tid >> 6;
  const int b    = blockIdx.z;
  const int o0   = blockIdx.y * 256;
  const int y0   = blockIdx.x * 2;
  const int wave_og = (wv & 1) * 8;    // og_local base (8 og = 128 o per wave)
  const int wn_py   = wv >> 1;         // output row within the 2-row tile

  const u16* xb = xh + (size_t)b * (PW * PW * CIN);
  // wAf slice for (b, *, *, og base o0/16)
  const u16* wb = wAf + (((size_t)b * 16 * 9 * 32) + (o0 >> 4)) * 512;

  f32x4 acc[8][4];
#pragma unroll
  for (int mi = 0; mi < 8; ++mi)
#pragma unroll
    for (int ni = 0; ni < 4; ++ni) acc[mi][ni] = (f32x4){0.f, 0.f, 0.f, 0.f};

  const int l15 = lane & 15;
  const int q   = lane >> 4;

  for (int ic = 0; ic < 16; ++ic) {
    // ---- stage Bs: 4 rows x 66 cols x 32 ch, rows padded to 40 el -------
    {
      const u16* src0 = xb + (size_t)y0 * PW * CIN + ic * 32;
#pragma unroll
      for (int r = 0; r < 5; ++r) {
        const int id = r * 256 + tid;           // chunk id 0..1279
        const int rc = id / 5, pos = id % 5;
        const int k  = (pos < 4) ? pos : 0;     // pos==4 -> pad, dup fetch
        async16(src0 + (size_t)rc * CIN + k * 8, &Bs[id * 8]);
      }
      { // overlap round covering chunks 1064..1319 (idempotent rewrite)
        const int id = 1064 + tid;
        const int rc = id / 5, pos = id % 5;
        const int k  = (pos < 4) ? pos : 0;
        async16(src0 + (size_t)rc * CIN + k * 8, &Bs[id * 8]);
      }
      // ---- stage A tap 0 into buf 0: 16 KB contiguous ------------------
      const u16* asrc = wb + (size_t)(ic * 9 + 0) * (32 * 512);
#pragma unroll
      for (int r = 0; r < 4; ++r)
        async16(asrc + (r * 256 + tid) * 8, &Asf[0][(r * 256 + tid) * 8]);
    }
    __syncthreads();                            // drain all staging

#pragma unroll
    for (int tap = 0; tap < 9; ++tap) {
      const int cur = tap & 1;
      if (tap < 8) {                            // prefetch next tap's A
        const u16* asrc = wb + (size_t)(ic * 9 + tap + 1) * (32 * 512);
#pragma unroll
        for (int r = 0; r < 4; ++r)
          async16(asrc + (r * 256 + tid) * 8, &Asf[cur ^ 1][(r * 256 + tid) * 8]);
      }
      const int ky = tap / 3, kx = tap % 3;

      bf16x8 bfrag[4];
#pragma unroll
      for (int ni = 0; ni < 4; ++ni) {
        const int rc = (wn_py + ky) * PW + ni * 16 + l15 + kx;
        bfrag[ni] = *(const bf16x8*)&Bs[rc * 40 + q * 8];
      }
#pragma unroll
      for (int mi = 0; mi < 8; ++mi) {
        const bf16x8 afrag =
            *(const bf16x8*)&Asf[cur][((wave_og + mi) * 64 + lane) * 8];
#pragma unroll
        for (int ni = 0; ni < 4; ++ni)
          acc[mi][ni] = __builtin_amdgcn_mfma_f32_16x16x32_bf16(
              afrag, bfrag[ni], acc[mi][ni], 0, 0, 0);
      }
      __syncthreads();   // drains vmcnt: next-tap A complete; frees cur buf
    }
  }

  // epilogue: D col = lane&15 (pixel x), row = q*4+reg (o); fp32 out
  const int y = y0 + wn_py;
#pragma unroll
  for (int mi = 0; mi < 8; ++mi) {
#pragma unroll
    for (int r = 0; r < 4; ++r) {
      const int o = o0 + (wv & 1) * 128 + mi * 16 + q * 4 + r;
      const float bv = bias[o];
      const size_t obase = (((size_t)b * COUT + o) * HW_ + y) * HW_;
#pragma unroll
      for (int ni = 0; ni < 4; ++ni)
        out[obase + ni * 16 + l15] = acc[mi][ni][r] + bv;
    }
  }
}

// ---------------------------------------------------------------------------
extern "C" void kernel_launch(void* const* d_in, const int* in_sizes, int n_in,
                              void* d_out, int out_size, void* d_ws, size_t ws_size,
                              hipStream_t stream) {
  const float* x    = (const float*)d_in[0];   // [16][512][64][64] fp32
  const float* s    = (const float*)d_in[1];   // [16][512] fp32
  const float* w    = (const float*)d_in[2];   // [512][512][3][3] fp32
  const float* bias = (const float*)d_in[3];   // [512] fp32
  float* out = (float*)d_out;                  // [16][512][64][64] fp32

  u16*   xh   = (u16*)d_ws;                    // padded NHWC bf16 input
  u16*   wAf  = xh + XH_ELEMS;                 // frag-ordered bf16 weights
  float* q    = (float*)(wAf + WA_ELEMS);      // 512x512 fp32
  float* sinv = q + 512 * 512;                 // 16x512 fp32

  zero_border<<<(B_ * 260 * 64 + 255) / 256, 256, 0, stream>>>(xh);
  transpose_x<<<dim3(8, 64, 16), 256, 0, stream>>>(x, xh);
  wsq_kernel<<<1024, 256, 0, stream>>>(w, q);
  sigma_kernel<<<2048, 256, 0, stream>>>(q, s, sinv);
  write_wAf<<<dim3(144, 8, 16), 256, 0, stream>>>(w, s, sinv, wAf);
  modconv_mfma<<<dim3(32, 2, 16), 256, 0, stream>>>(xh, wAf, bias, out);
}